// Round 14
// baseline (82.816 us; speedup 1.0000x reference)
//
#include <hip/hip_runtime.h>
#include <hip/hip_bf16.h>
#include <math.h>

#define G 64
#define NNODE 256      // nodes per graph (= O)
#define D_IN 128
#define HDIM 64
#define HEADS 4
#define E_PER 8192
#define NUM_NODES (G * NNODE)
#define E_TOTAL (G * E_PER)
#define BN_EPS 1e-5f

typedef __attribute__((ext_vector_type(8))) short bf16x8;
typedef __attribute__((ext_vector_type(4))) float f32x4;

__device__ __forceinline__ float lrelu02(float x) { return x > 0.f ? x : 0.2f * x; }
__device__ __forceinline__ unsigned short f2bf(float f) {
    unsigned u = __float_as_uint(f);
    return (unsigned short)((u + 0x7FFFu + ((u >> 16) & 1u)) >> 16);
}
__device__ __forceinline__ unsigned long long pk4(float a, float b, float c, float d) {
    return (unsigned long long)f2bf(a)
         | ((unsigned long long)f2bf(b) << 16)
         | ((unsigned long long)f2bf(c) << 32)
         | ((unsigned long long)f2bf(d) << 48);
}

// ======================= K0: fused setup =========================
__global__ __launch_bounds__(512) void setup_kernel(
    const int* __restrict__ eidx, unsigned int* __restrict__ cntm,
    const float* __restrict__ omics, const float* __restrict__ w,
    const float* __restrict__ b, const float* __restrict__ rot,
    const float* __restrict__ gamma, const float* __restrict__ beta,
    const float* __restrict__ mean, const float* __restrict__ var,
    unsigned short* __restrict__ xb,
    const float* __restrict__ w1, const float* __restrict__ w2,
    unsigned short* __restrict__ wt1, unsigned short* __restrict__ wt2)
{
    __shared__ union {
        struct { float Wl[D_IN * HDIM]; float Om[G * 132]; } enc;   // 65 KB
        unsigned cw[NNODE * 64];                                     // 64 KB
    } sm;
    int blk = blockIdx.x;
    int t = threadIdx.x;

    if (blk < G) {
        int g = blk;
        float4 z4 = make_float4(0.f, 0.f, 0.f, 0.f);
        for (int i = t; i < 4096; i += 512) ((float4*)sm.cw)[i] = z4;
        __syncthreads();
        const int* srcp = eidx + (size_t)g * E_PER;
        const int* dstp = eidx + E_TOTAL + (size_t)g * E_PER;
        int base = g * NNODE;
        for (int e = t; e < E_PER; e += 512) {
            int s = srcp[e] - base, d = dstp[e] - base;
            atomicAdd(&sm.cw[(d << 6) + (s >> 2)], 1u << ((s & 3) * 8));
        }
        __syncthreads();
        for (int i = t; i < 4096; i += 512)
            ((float4*)(cntm + (size_t)g * 16384))[i] = ((const float4*)sm.cw)[i];
    } else if (blk < G + 256) {
        int o = blk - G;
        for (int i = t; i < D_IN * HDIM / 4; i += 512)
            ((float4*)sm.enc.Wl)[i] = ((const float4*)(w + (size_t)o * D_IN * HDIM))[i];
        for (int i = t; i < G * (D_IN / 4); i += 512) {
            int g = i >> 5, dq = i & 31;
            *((float4*)(sm.enc.Om + g * 132) + dq) =
                ((const float4*)(omics + ((size_t)g * NNODE + o) * D_IN))[dq];
        }
        __syncthreads();

        int cq = t & 15, gs = t >> 4;
        float4 acc[2];
        acc[0] = make_float4(0.f, 0.f, 0.f, 0.f);
        acc[1] = make_float4(0.f, 0.f, 0.f, 0.f);

        for (int d = 0; d < D_IN; ++d) {
            float4 wv = *(const float4*)&sm.enc.Wl[d * 64 + cq * 4];
            #pragma unroll
            for (int gi = 0; gi < 2; ++gi) {
                float ov = sm.enc.Om[(gi * 32 + gs) * 132 + d];
                acc[gi].x = fmaf(ov, wv.x, acc[gi].x);
                acc[gi].y = fmaf(ov, wv.y, acc[gi].y);
                acc[gi].z = fmaf(ov, wv.z, acc[gi].z);
                acc[gi].w = fmaf(ov, wv.w, acc[gi].w);
            }
        }

        float4 bv = ((const float4*)b)[o * 16 + cq];
        float4 rv = ((const float4*)rot)[o * 16 + cq];
        float4 mv = ((const float4*)mean)[o * 16 + cq];
        float4 vv = ((const float4*)var)[o * 16 + cq];
        float4 gv = ((const float4*)gamma)[o * 16 + cq];
        float4 be = ((const float4*)beta)[o * 16 + cq];
        float4 sc, kk;
        sc.x = cosf(rv.x) + sinf(rv.x); sc.y = cosf(rv.y) + sinf(rv.y);
        sc.z = cosf(rv.z) + sinf(rv.z); sc.w = cosf(rv.w) + sinf(rv.w);
        kk.x = gv.x * rsqrtf(vv.x + BN_EPS); kk.y = gv.y * rsqrtf(vv.y + BN_EPS);
        kk.z = gv.z * rsqrtf(vv.z + BN_EPS); kk.w = gv.w * rsqrtf(vv.w + BN_EPS);

        #pragma unroll
        for (int gi = 0; gi < 2; ++gi) {
            int g = gi * 32 + gs;
            float4 v;
            v.x = fmaxf((acc[gi].x + bv.x) * sc.x, 0.f);
            v.y = fmaxf((acc[gi].y + bv.y) * sc.y, 0.f);
            v.z = fmaxf((acc[gi].z + bv.z) * sc.z, 0.f);
            v.w = fmaxf((acc[gi].w + bv.w) * sc.w, 0.f);
            v.x = (v.x - mv.x) * kk.x + be.x;
            v.y = (v.y - mv.y) * kk.y + be.y;
            v.z = (v.z - mv.z) * kk.z + be.z;
            v.w = (v.w - mv.w) * kk.w + be.w;
            *(unsigned long long*)&xb[((size_t)(g * NNODE + o)) * 64 + cq * 4] =
                pk4(v.x, v.y, v.z, v.w);
        }
    } else {
        int pb = blk - (G + 256);
        int i0 = pb * 2048 + t;
        #pragma unroll
        for (int it = 0; it < 4; ++it) {
            int i = i0 + it * 512;
            int c = i >> 6, k = i & 63;
            wt1[c * 64 + k] = f2bf(w1[k * 256 + c]);
            int c2 = i >> 8, k2 = i & 255;
            wt2[c2 * 256 + k2] = f2bf(w2[k2 * 64 + c2]);
        }
    }
}

// ======================= K1: GAT1 fused lin+edge =================
// grid (G, HEADS, 4), 512 thr, ~70 KB LDS (2 blocks/CU).
// Phase 1: ht[c][s] = (xb @ wt1[head])^T via MFMA (A,B from global),
//          as/ad logits accumulated in-register -> LDS.
// Phase 2: dense-count Mb fill -> M@H MFMA (+ones for den) -> ELU -> x2b.
__global__ __launch_bounds__(512) void gat1_fused(
    const unsigned short* __restrict__ xb, const unsigned short* __restrict__ wt1,
    const unsigned int* __restrict__ cntm,
    const float* __restrict__ att_s, const float* __restrict__ att_d,
    const float* __restrict__ bias1, unsigned short* __restrict__ x2b)
{
    int g = blockIdx.x, head = blockIdx.y, q = blockIdx.z;
    __shared__ unsigned short ht[64 * 256];    // 32 KB
    __shared__ unsigned short Mb[64 * 256];    // 32 KB (aliased as xs)
    __shared__ float asl[NNODE], adl[NNODE], u1[NNODE], u2[NNODE];
    __shared__ float v1[NNODE], v2[NNODE];
    __shared__ float wred[8];
    unsigned short* xs = Mb;
    int t = threadIdx.x;
    int r0 = q * 64;
    int w = t >> 6, l = t & 63;
    int lrow = l & 15, lk = l >> 4;

    // ---------- phase 1: linear via MFMA ----------
    {
        f32x4 acc[2][4];
        #pragma unroll
        for (int mi = 0; mi < 2; ++mi)
            #pragma unroll
            for (int cj = 0; cj < 4; ++cj) {
                f32x4 z = {0.f, 0.f, 0.f, 0.f};
                acc[mi][cj] = z;
            }
        #pragma unroll
        for (int kb = 0; kb < 2; ++kb) {
            int kslot = (kb * 4 + lk) * 8;
            bf16x8 bfrag[4];
            #pragma unroll
            for (int cj = 0; cj < 4; ++cj)
                bfrag[cj] = *(const bf16x8*)&wt1[(head * 64 + cj * 16 + lrow) * 64 + kslot];
            #pragma unroll
            for (int mi = 0; mi < 2; ++mi) {
                int s = (2 * w + mi) * 16 + lrow;
                bf16x8 a = *(const bf16x8*)&xb[(size_t)(g * NNODE + s) * 64 + kslot];
                #pragma unroll
                for (int cj = 0; cj < 4; ++cj)
                    acc[mi][cj] = __builtin_amdgcn_mfma_f32_16x16x32_bf16(
                        a, bfrag[cj], acc[mi][cj], 0, 0, 0);
            }
        }
        // ht write + as/ad logits
        #pragma unroll
        for (int mi = 0; mi < 2; ++mi) {
            int s0 = (2 * w + mi) * 16 + lk * 4;
            float asv[4] = {0.f, 0.f, 0.f, 0.f};
            float adv[4] = {0.f, 0.f, 0.f, 0.f};
            #pragma unroll
            for (int cj = 0; cj < 4; ++cj) {
                int c = cj * 16 + lrow;
                *(unsigned long long*)&ht[c * 256 + (((s0 >> 3) ^ (c & 31)) << 3) + (s0 & 7)] =
                    pk4(acc[mi][cj][0], acc[mi][cj][1], acc[mi][cj][2], acc[mi][cj][3]);
                float av = att_s[head * 64 + c], dv = att_d[head * 64 + c];
                #pragma unroll
                for (int r = 0; r < 4; ++r) {
                    asv[r] = fmaf(acc[mi][cj][r], av, asv[r]);
                    adv[r] = fmaf(acc[mi][cj][r], dv, adv[r]);
                }
            }
            #pragma unroll
            for (int r = 0; r < 4; ++r) {
                float a = asv[r], d = adv[r];
                a += __shfl_xor(a, 1); a += __shfl_xor(a, 2);
                a += __shfl_xor(a, 4); a += __shfl_xor(a, 8);
                d += __shfl_xor(d, 1); d += __shfl_xor(d, 2);
                d += __shfl_xor(d, 4); d += __shfl_xor(d, 8);
                if (lrow == 0) { asl[s0 + r] = a; adl[s0 + r] = d; }
            }
        }
    }
    __syncthreads();

    // ---------- softmax factor vectors ----------
    {
        float mv = (t < NNODE) ? asl[t] : -1e30f;
        #pragma unroll
        for (int d = 32; d; d >>= 1) mv = fmaxf(mv, __shfl_xor(mv, d));
        if ((t & 63) == 0) wred[t >> 6] = mv;
    }
    __syncthreads();
    if (t < NNODE) {
        float M = fmaxf(fmaxf(wred[0], wred[1]), fmaxf(wred[2], wred[3]));
        float vd = adl[t], va = asl[t];
        float mt = lrelu02(M + vd);
        v1[t] = __expf(vd - mt);
        v2[t] = __expf(0.2f * vd - mt);
        u1[t] = __expf(va);
        u2[t] = __expf(0.2f * va);
    }
    __syncthreads();

    // ---------- phase 2: edge aggregation ----------
    int mt = w & 3, nb = (w >> 2) * 2;
    int ar = mt * 16 + lrow;
    int c0 = nb * 16 + lrow, c1 = c0 + 16;
    float b0v = bias1[head * 64 + c0], b1v = bias1[head * 64 + c1];
    const bf16x8 onev = {(short)0x3F80, (short)0x3F80, (short)0x3F80, (short)0x3F80,
                         (short)0x3F80, (short)0x3F80, (short)0x3F80, (short)0x3F80};

    for (int ri = w; ri < 64; ri += 8) {
        int d = r0 + ri;
        unsigned cwv = cntm[(((size_t)g * NNODE + d) << 6) + l];
        float adv = adl[d], vd1 = v1[d], vd2 = v2[d];
        float4 as4 = ((const float4*)asl)[l];
        float4 u14 = ((const float4*)u1)[l];
        float4 u24 = ((const float4*)u2)[l];
        float p0 = (float)(cwv & 0xFFu) *
                   ((as4.x + adv > 0.f) ? u14.x * vd1 : u24.x * vd2);
        float p1 = (float)((cwv >> 8) & 0xFFu) *
                   ((as4.y + adv > 0.f) ? u14.y * vd1 : u24.y * vd2);
        float p2 = (float)((cwv >> 16) & 0xFFu) *
                   ((as4.z + adv > 0.f) ? u14.z * vd1 : u24.z * vd2);
        float p3 = (float)(cwv >> 24) *
                   ((as4.w + adv > 0.f) ? u14.w * vd1 : u24.w * vd2);
        *(unsigned long long*)&Mb[ri * 256 + (((l >> 1) ^ (ri & 7)) << 3)
                                  + ((l & 1) << 2)] = pk4(p0, p1, p2, p3);
    }
    __syncthreads();

    f32x4 acc0 = {0.f, 0.f, 0.f, 0.f};
    f32x4 acc1 = {0.f, 0.f, 0.f, 0.f};
    f32x4 accd = {0.f, 0.f, 0.f, 0.f};
    #pragma unroll
    for (int kb = 0; kb < 8; ++kb) {
        int oct = kb * 4 + lk;
        bf16x8 a = *(const bf16x8*)&Mb[ar * 256 + ((oct ^ (ar & 7)) << 3)];
        bf16x8 b0 = *(const bf16x8*)&ht[c0 * 256 + ((oct ^ (c0 & 31)) << 3)];
        bf16x8 b1 = *(const bf16x8*)&ht[c1 * 256 + ((oct ^ (c1 & 31)) << 3)];
        accd = __builtin_amdgcn_mfma_f32_16x16x32_bf16(a, onev, accd, 0, 0, 0);
        acc0 = __builtin_amdgcn_mfma_f32_16x16x32_bf16(a, b0, acc0, 0, 0, 0);
        acc1 = __builtin_amdgcn_mfma_f32_16x16x32_bf16(a, b1, acc1, 0, 0, 0);
    }
    __syncthreads();   // alias safety
    #pragma unroll
    for (int r = 0; r < 4; ++r) {
        int rl = mt * 16 + lk * 4 + r;
        float inv = 1.f / (accd[r] + 1e-16f);
        float o0 = acc0[r] * inv + b0v;
        float o1 = acc1[r] * inv + b1v;
        o0 = o0 > 0.f ? o0 : expm1f(o0);
        o1 = o1 > 0.f ? o1 : expm1f(o1);
        xs[rl * 64 + c0] = f2bf(o0);
        xs[rl * 64 + c1] = f2bf(o1);
    }
    __syncthreads();
    {
        int row = t >> 3, cg = t & 7;
        bf16x8 v = *(const bf16x8*)&xs[row * 64 + cg * 8];
        *(bf16x8*)&x2b[(size_t)(g * NNODE + r0 + row) * 256 + head * 64 + cg * 8] = v;
    }
}

// ======================= K2: GAT2 fused lin+edge+pool ============
// grid (G, 8), 512 thr, ~54 KB LDS. Phase 1: ht2[c][s] via MFMA (K=256).
__global__ __launch_bounds__(512) void gat2_fused(
    const unsigned short* __restrict__ x2b, const unsigned short* __restrict__ wt2,
    const unsigned int* __restrict__ cntm,
    const float* __restrict__ att_s, const float* __restrict__ att_d,
    float* __restrict__ pl8)
{
    int g = blockIdx.x, by = blockIdx.y;
    __shared__ unsigned short ht[64 * 256];    // 32 KB
    __shared__ unsigned short Mb[32 * 256];    // 16 KB
    __shared__ float asl[NNODE], adl[NNODE], u1[NNODE], u2[NNODE];
    __shared__ float v1[NNODE], v2[NNODE];
    __shared__ float wred[8];
    __shared__ float pool[64];
    int t = threadIdx.x;
    int w = t >> 6, l = t & 63;
    int lrow = l & 15, lk = l >> 4;
    int r0 = by * 32;
    if (t < 64) pool[t] = 0.f;

    // ---------- phase 1: linear (K=256) ----------
    {
        f32x4 acc[2][4];
        #pragma unroll
        for (int mi = 0; mi < 2; ++mi)
            #pragma unroll
            for (int cj = 0; cj < 4; ++cj) {
                f32x4 z = {0.f, 0.f, 0.f, 0.f};
                acc[mi][cj] = z;
            }
        for (int kb = 0; kb < 8; ++kb) {
            int kslot = (kb * 4 + lk) * 8;
            bf16x8 bfrag[4];
            #pragma unroll
            for (int cj = 0; cj < 4; ++cj)
                bfrag[cj] = *(const bf16x8*)&wt2[(cj * 16 + lrow) * 256 + kslot];
            #pragma unroll
            for (int mi = 0; mi < 2; ++mi) {
                int s = (2 * w + mi) * 16 + lrow;
                bf16x8 a = *(const bf16x8*)&x2b[(size_t)(g * NNODE + s) * 256 + kslot];
                #pragma unroll
                for (int cj = 0; cj < 4; ++cj)
                    acc[mi][cj] = __builtin_amdgcn_mfma_f32_16x16x32_bf16(
                        a, bfrag[cj], acc[mi][cj], 0, 0, 0);
            }
        }
        #pragma unroll
        for (int mi = 0; mi < 2; ++mi) {
            int s0 = (2 * w + mi) * 16 + lk * 4;
            float asv[4] = {0.f, 0.f, 0.f, 0.f};
            float adv[4] = {0.f, 0.f, 0.f, 0.f};
            #pragma unroll
            for (int cj = 0; cj < 4; ++cj) {
                int c = cj * 16 + lrow;
                *(unsigned long long*)&ht[c * 256 + (((s0 >> 3) ^ (c & 31)) << 3) + (s0 & 7)] =
                    pk4(acc[mi][cj][0], acc[mi][cj][1], acc[mi][cj][2], acc[mi][cj][3]);
                float av = att_s[c], dv = att_d[c];
                #pragma unroll
                for (int r = 0; r < 4; ++r) {
                    asv[r] = fmaf(acc[mi][cj][r], av, asv[r]);
                    adv[r] = fmaf(acc[mi][cj][r], dv, adv[r]);
                }
            }
            #pragma unroll
            for (int r = 0; r < 4; ++r) {
                float a = asv[r], d = adv[r];
                a += __shfl_xor(a, 1); a += __shfl_xor(a, 2);
                a += __shfl_xor(a, 4); a += __shfl_xor(a, 8);
                d += __shfl_xor(d, 1); d += __shfl_xor(d, 2);
                d += __shfl_xor(d, 4); d += __shfl_xor(d, 8);
                if (lrow == 0) { asl[s0 + r] = a; adl[s0 + r] = d; }
            }
        }
    }
    __syncthreads();

    {
        float mv = (t < NNODE) ? asl[t] : -1e30f;
        #pragma unroll
        for (int d = 32; d; d >>= 1) mv = fmaxf(mv, __shfl_xor(mv, d));
        if ((t & 63) == 0) wred[t >> 6] = mv;
    }
    __syncthreads();
    if (t < NNODE) {
        float M = fmaxf(fmaxf(wred[0], wred[1]), fmaxf(wred[2], wred[3]));
        float vd = adl[t], va = asl[t];
        float mt = lrelu02(M + vd);
        v1[t] = __expf(vd - mt);
        v2[t] = __expf(0.2f * vd - mt);
        u1[t] = __expf(va);
        u2[t] = __expf(0.2f * va);
    }
    __syncthreads();

    // ---------- phase 2: edge + pool ----------
    for (int ri = w; ri < 32; ri += 8) {
        int d = r0 + ri;
        unsigned cwv = cntm[(((size_t)g * NNODE + d) << 6) + l];
        float adv = adl[d], vd1 = v1[d], vd2 = v2[d];
        float4 as4 = ((const float4*)asl)[l];
        float4 u14 = ((const float4*)u1)[l];
        float4 u24 = ((const float4*)u2)[l];
        float p0 = (float)(cwv & 0xFFu) *
                   ((as4.x + adv > 0.f) ? u14.x * vd1 : u24.x * vd2);
        float p1 = (float)((cwv >> 8) & 0xFFu) *
                   ((as4.y + adv > 0.f) ? u14.y * vd1 : u24.y * vd2);
        float p2 = (float)((cwv >> 16) & 0xFFu) *
                   ((as4.z + adv > 0.f) ? u14.z * vd1 : u24.z * vd2);
        float p3 = (float)(cwv >> 24) *
                   ((as4.w + adv > 0.f) ? u14.w * vd1 : u24.w * vd2);
        *(unsigned long long*)&Mb[ri * 256 + (((l >> 1) ^ (ri & 7)) << 3)
                                  + ((l & 1) << 2)] = pk4(p0, p1, p2, p3);
    }
    __syncthreads();

    const bf16x8 onev = {(short)0x3F80, (short)0x3F80, (short)0x3F80, (short)0x3F80,
                         (short)0x3F80, (short)0x3F80, (short)0x3F80, (short)0x3F80};
    int mt = w & 1, nt = w >> 1;
    f32x4 acc = {0.f, 0.f, 0.f, 0.f};
    f32x4 accd = {0.f, 0.f, 0.f, 0.f};
    int ar = mt * 16 + lrow;
    int c = nt * 16 + lrow;
    #pragma unroll
    for (int kb = 0; kb < 8; ++kb) {
        int oct = kb * 4 + lk;
        bf16x8 a = *(const bf16x8*)&Mb[ar * 256 + ((oct ^ (ar & 7)) << 3)];
        bf16x8 b = *(const bf16x8*)&ht[c * 256 + ((oct ^ (c & 31)) << 3)];
        accd = __builtin_amdgcn_mfma_f32_16x16x32_bf16(a, onev, accd, 0, 0, 0);
        acc = __builtin_amdgcn_mfma_f32_16x16x32_bf16(a, b, acc, 0, 0, 0);
    }
    float ps = 0.f;
    #pragma unroll
    for (int r = 0; r < 4; ++r)
        ps = fmaf(acc[r], 1.f / (accd[r] + 1e-16f), ps);
    ps += __shfl_xor(ps, 16);
    ps += __shfl_xor(ps, 32);
    if (l < 16) atomicAdd(&pool[nt * 16 + lrow], ps);
    __syncthreads();
    if (t < 64) pl8[(size_t)(g * 8 + by) * 64 + t] = pool[t];
}

// ======================= K3: pool-combine + classifier ===========
__global__ __launch_bounds__(64) void cls_kernel(
    const float* __restrict__ pl8, const float* __restrict__ bias2,
    const float* __restrict__ w1, const float* __restrict__ b1,
    const float* __restrict__ w2, const float* __restrict__ b2,
    float* __restrict__ outv, float* __restrict__ pooled)
{
    int g = blockIdx.x, c = threadIdx.x;
    float po = 0.f;
    #pragma unroll
    for (int q = 0; q < 8; ++q) po += pl8[(size_t)(g * 8 + q) * 64 + c];
    po = po * (1.f / 256.f) + bias2[c];
    pooled[g * 64 + c] = po;
    __shared__ float poL[64];
    poL[c] = po;
    __syncthreads();
    float acc = b1[c];
    for (int k = 0; k < 64; ++k) acc = fmaf(poL[k], w1[k * 64 + c], acc);
    acc = fmaxf(acc, 0.f);
    float contrib = acc * w2[c];
    #pragma unroll
    for (int d = 32; d; d >>= 1) contrib += __shfl_xor(contrib, d);
    if (c == 0) outv[g] = 1.f / (1.f + __expf(-contrib));
}

extern "C" void kernel_launch(void* const* d_in, const int* in_sizes, int n_in,
                              void* d_out, int out_size, void* d_ws, size_t ws_size,
                              hipStream_t stream) {
    const float* omics   = (const float*)d_in[0];
    const float* w_omics = (const float*)d_in[1];
    const float* b_omics = (const float*)d_in[2];
    const float* rot     = (const float*)d_in[3];
    const float* bn_g    = (const float*)d_in[4];
    const float* bn_b    = (const float*)d_in[5];
    const float* bn_m    = (const float*)d_in[6];
    const float* bn_v    = (const float*)d_in[7];
    const float* gat1_w  = (const float*)d_in[8];
    const float* att_s1  = (const float*)d_in[9];
    const float* att_d1  = (const float*)d_in[10];
    const float* bias1   = (const float*)d_in[11];
    const float* gat2_w  = (const float*)d_in[12];
    const float* att_s2  = (const float*)d_in[13];
    const float* att_d2  = (const float*)d_in[14];
    const float* bias2   = (const float*)d_in[15];
    const float* cls_w1  = (const float*)d_in[16];
    const float* cls_b1  = (const float*)d_in[17];
    const float* cls_w2  = (const float*)d_in[18];
    const float* cls_b2  = (const float*)d_in[19];
    const int*   eidx    = (const int*)d_in[20];

    float* ws = (float*)d_ws;
    size_t o_xb   = 0;                                        // bf16 NUM_NODES*64
    size_t o_x2b  = o_xb  + (size_t)NUM_NODES * 64 / 2;       // bf16 NUM_NODES*256
    size_t o_pl8  = o_x2b + (size_t)NUM_NODES * 256 / 2;
    size_t o_cnt  = o_pl8 + (size_t)G * 8 * 64;               // u32 G*16384
    size_t o_wt1  = o_cnt + (size_t)G * 16384;
    size_t o_wt2  = o_wt1 + 8192;

    unsigned short* xb  = (unsigned short*)(ws + o_xb);
    unsigned short* x2b = (unsigned short*)(ws + o_x2b);
    float* pl8 = ws + o_pl8;
    unsigned int* cntm = (unsigned int*)(ws + o_cnt);
    unsigned short* wt1 = (unsigned short*)(ws + o_wt1);
    unsigned short* wt2 = (unsigned short*)(ws + o_wt2);

    float* outv   = (float*)d_out;        // [64]
    float* pooled = (float*)d_out + G;    // [64*64]

    setup_kernel<<<G + 256 + 8, 512, 0, stream>>>(
        eidx, cntm,
        omics, w_omics, b_omics, rot, bn_g, bn_b, bn_m, bn_v, xb,
        gat1_w, gat2_w, wt1, wt2);
    gat1_fused<<<dim3(G, HEADS, 4), 512, 0, stream>>>(
        xb, wt1, cntm, att_s1, att_d1, bias1, x2b);
    gat2_fused<<<dim3(G, 8), 512, 0, stream>>>(
        x2b, wt2, cntm, att_s2, att_d2, pl8);
    cls_kernel<<<G, 64, 0, stream>>>(pl8, bias2, cls_w1, cls_b1, cls_w2, cls_b2,
                                     outv, pooled);
}

// Round 15
// 61.748 us; speedup vs baseline: 1.3412x; 1.3412x over previous
//
#include <hip/hip_runtime.h>
#include <hip/hip_bf16.h>
#include <math.h>

#define G 64
#define NNODE 256      // nodes per graph (= O)
#define D_IN 128
#define HDIM 64
#define HEADS 4
#define E_PER 8192
#define NUM_NODES (G * NNODE)
#define E_TOTAL (G * E_PER)
#define BN_EPS 1e-5f

typedef __attribute__((ext_vector_type(8))) short bf16x8;
typedef __attribute__((ext_vector_type(4))) float f32x4;

__device__ __forceinline__ float lrelu02(float x) { return x > 0.f ? x : 0.2f * x; }
__device__ __forceinline__ unsigned short f2bf(float f) {
    unsigned u = __float_as_uint(f);
    return (unsigned short)((u + 0x7FFFu + ((u >> 16) & 1u)) >> 16);
}
__device__ __forceinline__ unsigned long long pk4(float a, float b, float c, float d) {
    return (unsigned long long)f2bf(a)
         | ((unsigned long long)f2bf(b) << 16)
         | ((unsigned long long)f2bf(c) << 32)
         | ((unsigned long long)f2bf(d) << 48);
}

// ======================= K0: fused setup =========================
// blocks [0,64): dense edge-count matrix (packed u8);
// [64,320): omics encoder; [320,328): weight transpose.
__global__ __launch_bounds__(512) void setup_kernel(
    const int* __restrict__ eidx, unsigned int* __restrict__ cntm,
    const float* __restrict__ omics, const float* __restrict__ w,
    const float* __restrict__ b, const float* __restrict__ rot,
    const float* __restrict__ gamma, const float* __restrict__ beta,
    const float* __restrict__ mean, const float* __restrict__ var,
    unsigned short* __restrict__ xb,
    const float* __restrict__ w1, const float* __restrict__ w2,
    unsigned short* __restrict__ wt1, unsigned short* __restrict__ wt2)
{
    __shared__ union {
        struct { float Wl[D_IN * HDIM]; float Om[G * 132]; } enc;   // 65 KB
        unsigned cw[NNODE * 64];                                     // 64 KB
    } sm;
    int blk = blockIdx.x;
    int t = threadIdx.x;

    if (blk < G) {
        int g = blk;
        float4 z4 = make_float4(0.f, 0.f, 0.f, 0.f);
        for (int i = t; i < 4096; i += 512) ((float4*)sm.cw)[i] = z4;
        __syncthreads();
        const int* srcp = eidx + (size_t)g * E_PER;
        const int* dstp = eidx + E_TOTAL + (size_t)g * E_PER;
        int base = g * NNODE;
        for (int e = t; e < E_PER; e += 512) {
            int s = srcp[e] - base, d = dstp[e] - base;
            atomicAdd(&sm.cw[(d << 6) + (s >> 2)], 1u << ((s & 3) * 8));
        }
        __syncthreads();
        for (int i = t; i < 4096; i += 512)
            ((float4*)(cntm + (size_t)g * 16384))[i] = ((const float4*)sm.cw)[i];
    } else if (blk < G + 256) {
        int o = blk - G;
        for (int i = t; i < D_IN * HDIM / 4; i += 512)
            ((float4*)sm.enc.Wl)[i] = ((const float4*)(w + (size_t)o * D_IN * HDIM))[i];
        for (int i = t; i < G * (D_IN / 4); i += 512) {
            int g = i >> 5, dq = i & 31;
            *((float4*)(sm.enc.Om + g * 132) + dq) =
                ((const float4*)(omics + ((size_t)g * NNODE + o) * D_IN))[dq];
        }
        __syncthreads();

        int cq = t & 15, gs = t >> 4;
        float4 acc[2];
        acc[0] = make_float4(0.f, 0.f, 0.f, 0.f);
        acc[1] = make_float4(0.f, 0.f, 0.f, 0.f);

        for (int d = 0; d < D_IN; ++d) {
            float4 wv = *(const float4*)&sm.enc.Wl[d * 64 + cq * 4];
            #pragma unroll
            for (int gi = 0; gi < 2; ++gi) {
                float ov = sm.enc.Om[(gi * 32 + gs) * 132 + d];
                acc[gi].x = fmaf(ov, wv.x, acc[gi].x);
                acc[gi].y = fmaf(ov, wv.y, acc[gi].y);
                acc[gi].z = fmaf(ov, wv.z, acc[gi].z);
                acc[gi].w = fmaf(ov, wv.w, acc[gi].w);
            }
        }

        float4 bv = ((const float4*)b)[o * 16 + cq];
        float4 rv = ((const float4*)rot)[o * 16 + cq];
        float4 mv = ((const float4*)mean)[o * 16 + cq];
        float4 vv = ((const float4*)var)[o * 16 + cq];
        float4 gv = ((const float4*)gamma)[o * 16 + cq];
        float4 be = ((const float4*)beta)[o * 16 + cq];
        float4 sc, kk;
        sc.x = cosf(rv.x) + sinf(rv.x); sc.y = cosf(rv.y) + sinf(rv.y);
        sc.z = cosf(rv.z) + sinf(rv.z); sc.w = cosf(rv.w) + sinf(rv.w);
        kk.x = gv.x * rsqrtf(vv.x + BN_EPS); kk.y = gv.y * rsqrtf(vv.y + BN_EPS);
        kk.z = gv.z * rsqrtf(vv.z + BN_EPS); kk.w = gv.w * rsqrtf(vv.w + BN_EPS);

        #pragma unroll
        for (int gi = 0; gi < 2; ++gi) {
            int g = gi * 32 + gs;
            float4 v;
            v.x = fmaxf((acc[gi].x + bv.x) * sc.x, 0.f);
            v.y = fmaxf((acc[gi].y + bv.y) * sc.y, 0.f);
            v.z = fmaxf((acc[gi].z + bv.z) * sc.z, 0.f);
            v.w = fmaxf((acc[gi].w + bv.w) * sc.w, 0.f);
            v.x = (v.x - mv.x) * kk.x + be.x;
            v.y = (v.y - mv.y) * kk.y + be.y;
            v.z = (v.z - mv.z) * kk.z + be.z;
            v.w = (v.w - mv.w) * kk.w + be.w;
            *(unsigned long long*)&xb[((size_t)(g * NNODE + o)) * 64 + cq * 4] =
                pk4(v.x, v.y, v.z, v.w);
        }
    } else {
        int pb = blk - (G + 256);
        int i0 = pb * 2048 + t;
        #pragma unroll
        for (int it = 0; it < 4; ++it) {
            int i = i0 + it * 512;
            int c = i >> 6, k = i & 63;
            wt1[c * 64 + k] = f2bf(w1[k * 256 + c]);
            int c2 = i >> 8, k2 = i & 255;
            wt2[c2 * 256 + k2] = f2bf(w2[k2 * 64 + c2]);
        }
    }
}

// ======================= K2: GAT1 linear via MFMA ================
__global__ __launch_bounds__(512) void gat1_lin_mfma(
    const unsigned short* __restrict__ xb, const unsigned short* __restrict__ wt1,
    const float* __restrict__ att_s, const float* __restrict__ att_d,
    unsigned short* __restrict__ ht1, float* __restrict__ as1, float* __restrict__ ad1)
{
    int blk = blockIdx.x;
    int n0 = blk * 64;
    int g = n0 >> 8, soff = n0 & 255;
    __shared__ unsigned short Ab[64 * 64];
    __shared__ unsigned short Bb[256 * 64];
    int t = threadIdx.x;
    {
        int node = t >> 3, kg = t & 7;
        bf16x8 v = *(const bf16x8*)&xb[(size_t)(n0 + node) * 64 + kg * 8];
        *(bf16x8*)&Ab[node * 64 + ((kg ^ (node & 7)) << 3)] = v;
    }
    for (int i = t; i < 2048; i += 512) {
        int c = i >> 3, kg = i & 7;
        bf16x8 v = *(const bf16x8*)&wt1[c * 64 + kg * 8];
        *(bf16x8*)&Bb[c * 64 + ((kg ^ (c & 7)) << 3)] = v;
    }
    __syncthreads();

    int w = t >> 6, l = t & 63;
    int lrow = l & 15, lk = l >> 4;
    int mt = w >> 1, hh0 = (w & 1) * 2;
    int arow = mt * 16 + lrow;
    float asp[2][4], adp[2][4];
    #pragma unroll
    for (int hi = 0; hi < 2; ++hi)
        #pragma unroll
        for (int r = 0; r < 4; ++r) { asp[hi][r] = 0.f; adp[hi][r] = 0.f; }

    for (int ntl = 0; ntl < 8; ++ntl) {
        int nt = (w & 1) * 8 + ntl;
        int c = nt * 16 + lrow;
        f32x4 acc = {0.f, 0.f, 0.f, 0.f};
        #pragma unroll
        for (int kb = 0; kb < 2; ++kb) {
            int kg = kb * 4 + lk;
            bf16x8 a = *(const bf16x8*)&Ab[arow * 64 + ((kg ^ (arow & 7)) << 3)];
            bf16x8 b = *(const bf16x8*)&Bb[c * 64 + ((kg ^ (c & 7)) << 3)];
            acc = __builtin_amdgcn_mfma_f32_16x16x32_bf16(a, b, acc, 0, 0, 0);
        }
        int head = c >> 6, ch = c & 63;
        int sb = soff + mt * 16 + lk * 4;
        *(unsigned long long*)&ht1[(size_t)((g * HEADS + head) * 64 + ch) * 256 + sb] =
            pk4(acc[0], acc[1], acc[2], acc[3]);
        float av = att_s[c], dv = att_d[c];
        int hi = ntl >> 2;
        #pragma unroll
        for (int r = 0; r < 4; ++r) {
            asp[hi][r] = fmaf(acc[r], av, asp[hi][r]);
            adp[hi][r] = fmaf(acc[r], dv, adp[hi][r]);
        }
    }
    #pragma unroll
    for (int hi = 0; hi < 2; ++hi)
        #pragma unroll
        for (int r = 0; r < 4; ++r) {
            float a = asp[hi][r], d = adp[hi][r];
            a += __shfl_xor(a, 1); a += __shfl_xor(a, 2);
            a += __shfl_xor(a, 4); a += __shfl_xor(a, 8);
            d += __shfl_xor(d, 1); d += __shfl_xor(d, 2);
            d += __shfl_xor(d, 4); d += __shfl_xor(d, 8);
            if (lrow == 0) {
                int node = n0 + mt * 16 + lk * 4 + r;
                as1[node * HEADS + hh0 + hi] = a;
                ad1[node * HEADS + hh0 + hi] = d;
            }
        }
}

// ======================= K3: GAT1 edge via dense-count MFMA ======
// grid (G, HEADS, 4): one dst-quarter per block. Unconditional fill
// covers all of Mb -> no zero pass.
__global__ __launch_bounds__(512) void gat1_edge_mfma(
    const unsigned short* __restrict__ ht1, const float* __restrict__ as1,
    const float* __restrict__ ad1, const unsigned int* __restrict__ cntm,
    const float* __restrict__ bias1, unsigned short* __restrict__ x2b)
{
    int g = blockIdx.x, head = blockIdx.y, q = blockIdx.z;
    __shared__ unsigned short ht[64 * 256];    // 32 KB
    __shared__ unsigned short Mb[64 * 256];    // 32 KB (aliased as xs in epilogue)
    __shared__ float asl[NNODE], adl[NNODE], u1[NNODE], u2[NNODE];
    __shared__ float v1[NNODE], v2[NNODE];
    __shared__ float wred[8];
    unsigned short* xs = Mb;
    int t = threadIdx.x;
    int r0 = q * 64;

    float va = -1e30f, vd = 0.f;
    if (t < NNODE) {
        va = as1[(g * NNODE + t) * HEADS + head];
        vd = ad1[(g * NNODE + t) * HEADS + head];
        asl[t] = va; adl[t] = vd;
    }
    {
        float mv = va;
        #pragma unroll
        for (int d = 32; d; d >>= 1) mv = fmaxf(mv, __shfl_xor(mv, d));
        if ((t & 63) == 0) wred[t >> 6] = mv;
    }
    __syncthreads();
    if (t < NNODE) {
        float M = fmaxf(fmaxf(wred[0], wred[1]), fmaxf(wred[2], wred[3]));
        float mt = lrelu02(M + vd);
        v1[t] = __expf(vd - mt);
        v2[t] = __expf(0.2f * vd - mt);
        u1[t] = __expf(va);
        u2[t] = __expf(0.2f * va);
    }
    for (int i = t; i < 2048; i += 512) {
        int c = i >> 5, sg = i & 31;
        bf16x8 v = *(const bf16x8*)&ht1[(size_t)((g * HEADS + head) * 64 + c) * 256 + sg * 8];
        *(bf16x8*)&ht[c * 256 + ((sg ^ (c & 31)) << 3)] = v;
    }
    __syncthreads();

    int w = t >> 6, l = t & 63;
    int lrow = l & 15, lk = l >> 4;
    int mt = w & 3, nb = (w >> 2) * 2;
    int ar = mt * 16 + lrow;
    int c0 = nb * 16 + lrow, c1 = c0 + 16;
    float b0v = bias1[head * 64 + c0], b1v = bias1[head * 64 + c1];
    const bf16x8 onev = {(short)0x3F80, (short)0x3F80, (short)0x3F80, (short)0x3F80,
                         (short)0x3F80, (short)0x3F80, (short)0x3F80, (short)0x3F80};

    // dense fill (unconditional: count 0 -> p 0), covers all of Mb
    for (int ri = w; ri < 64; ri += 8) {
        int d = r0 + ri;
        unsigned cwv = cntm[(((size_t)g * NNODE + d) << 6) + l];
        float adv = adl[d], vd1 = v1[d], vd2 = v2[d];
        float4 as4 = ((const float4*)asl)[l];
        float4 u14 = ((const float4*)u1)[l];
        float4 u24 = ((const float4*)u2)[l];
        float p0 = (float)(cwv & 0xFFu) *
                   ((as4.x + adv > 0.f) ? u14.x * vd1 : u24.x * vd2);
        float p1 = (float)((cwv >> 8) & 0xFFu) *
                   ((as4.y + adv > 0.f) ? u14.y * vd1 : u24.y * vd2);
        float p2 = (float)((cwv >> 16) & 0xFFu) *
                   ((as4.z + adv > 0.f) ? u14.z * vd1 : u24.z * vd2);
        float p3 = (float)(cwv >> 24) *
                   ((as4.w + adv > 0.f) ? u14.w * vd1 : u24.w * vd2);
        *(unsigned long long*)&Mb[ri * 256 + (((l >> 1) ^ (ri & 7)) << 3)
                                  + ((l & 1) << 2)] = pk4(p0, p1, p2, p3);
    }
    __syncthreads();

    f32x4 acc0 = {0.f, 0.f, 0.f, 0.f};
    f32x4 acc1 = {0.f, 0.f, 0.f, 0.f};
    f32x4 accd = {0.f, 0.f, 0.f, 0.f};
    #pragma unroll
    for (int kb = 0; kb < 8; ++kb) {
        int oct = kb * 4 + lk;
        bf16x8 a = *(const bf16x8*)&Mb[ar * 256 + ((oct ^ (ar & 7)) << 3)];
        bf16x8 b0 = *(const bf16x8*)&ht[c0 * 256 + ((oct ^ (c0 & 31)) << 3)];
        bf16x8 b1 = *(const bf16x8*)&ht[c1 * 256 + ((oct ^ (c1 & 31)) << 3)];
        accd = __builtin_amdgcn_mfma_f32_16x16x32_bf16(a, onev, accd, 0, 0, 0);
        acc0 = __builtin_amdgcn_mfma_f32_16x16x32_bf16(a, b0, acc0, 0, 0, 0);
        acc1 = __builtin_amdgcn_mfma_f32_16x16x32_bf16(a, b1, acc1, 0, 0, 0);
    }
    __syncthreads();   // alias safety: all Mb reads done before xs writes
    #pragma unroll
    for (int r = 0; r < 4; ++r) {
        int rl = mt * 16 + lk * 4 + r;
        float inv = 1.f / (accd[r] + 1e-16f);
        float o0 = acc0[r] * inv + b0v;
        float o1 = acc1[r] * inv + b1v;
        o0 = o0 > 0.f ? o0 : expm1f(o0);
        o1 = o1 > 0.f ? o1 : expm1f(o1);
        xs[rl * 64 + c0] = f2bf(o0);
        xs[rl * 64 + c1] = f2bf(o1);
    }
    __syncthreads();
    {
        int row = t >> 3, cg = t & 7;
        bf16x8 v = *(const bf16x8*)&xs[row * 64 + cg * 8];
        *(bf16x8*)&x2b[(size_t)(g * NNODE + r0 + row) * 256 + head * 64 + cg * 8] = v;
    }
}

// ======================= K4: GAT2 linear via MFMA ================
__global__ __launch_bounds__(512) void gat2_lin_mfma(
    const unsigned short* __restrict__ x2b, const unsigned short* __restrict__ wt2,
    const float* __restrict__ att_s, const float* __restrict__ att_d,
    unsigned short* __restrict__ ht2, float* __restrict__ as2, float* __restrict__ ad2)
{
    int blk = blockIdx.x;
    int n0 = blk * 64;
    int g = n0 >> 8, soff = n0 & 255;
    __shared__ unsigned short Ab[64 * 256];
    __shared__ unsigned short Bb[64 * 256];
    __shared__ float asr[64], adr[64];
    int t = threadIdx.x;
    for (int i = t; i < 2048; i += 512) {
        int node = i >> 5, kg = i & 31;
        bf16x8 v = *(const bf16x8*)&x2b[(size_t)(n0 + node) * 256 + kg * 8];
        *(bf16x8*)&Ab[node * 256 + ((kg ^ (node & 31)) << 3)] = v;
    }
    for (int i = t; i < 2048; i += 512) {
        int c = i >> 5, kg = i & 31;
        bf16x8 v = *(const bf16x8*)&wt2[c * 256 + kg * 8];
        *(bf16x8*)&Bb[c * 256 + ((kg ^ (c & 31)) << 3)] = v;
    }
    if (t < 64) { asr[t] = 0.f; adr[t] = 0.f; }
    __syncthreads();

    int w = t >> 6, l = t & 63;
    int lrow = l & 15, lk = l >> 4;
    int mt = w & 3, nb = (w >> 2) * 2;
    int ar = mt * 16 + lrow;
    float asp[2][4], adp[2][4];
    #pragma unroll
    for (int ni = 0; ni < 2; ++ni)
        #pragma unroll
        for (int r = 0; r < 4; ++r) { asp[ni][r] = 0.f; adp[ni][r] = 0.f; }

    #pragma unroll
    for (int ni = 0; ni < 2; ++ni) {
        int c = (nb + ni) * 16 + lrow;
        f32x4 acc = {0.f, 0.f, 0.f, 0.f};
        #pragma unroll
        for (int ks = 0; ks < 8; ++ks) {
            int kg = ks * 4 + lk;
            bf16x8 a = *(const bf16x8*)&Ab[ar * 256 + ((kg ^ (ar & 31)) << 3)];
            bf16x8 b = *(const bf16x8*)&Bb[c * 256 + ((kg ^ (c & 31)) << 3)];
            acc = __builtin_amdgcn_mfma_f32_16x16x32_bf16(a, b, acc, 0, 0, 0);
        }
        int sb = soff + mt * 16 + lk * 4;
        *(unsigned long long*)&ht2[(size_t)(g * 64 + c) * 256 + sb] =
            pk4(acc[0], acc[1], acc[2], acc[3]);
        float av = att_s[c], dv = att_d[c];
        #pragma unroll
        for (int r = 0; r < 4; ++r) {
            asp[ni][r] = fmaf(acc[r], av, asp[ni][r]);
            adp[ni][r] = fmaf(acc[r], dv, adp[ni][r]);
        }
    }
    #pragma unroll
    for (int ni = 0; ni < 2; ++ni)
        #pragma unroll
        for (int r = 0; r < 4; ++r) {
            float a = asp[ni][r], d = adp[ni][r];
            a += __shfl_xor(a, 1); a += __shfl_xor(a, 2);
            a += __shfl_xor(a, 4); a += __shfl_xor(a, 8);
            d += __shfl_xor(d, 1); d += __shfl_xor(d, 2);
            d += __shfl_xor(d, 4); d += __shfl_xor(d, 8);
            if (lrow == 0) {
                int rl = mt * 16 + lk * 4 + r;
                atomicAdd(&asr[rl], a);
                atomicAdd(&adr[rl], d);
            }
        }
    __syncthreads();
    if (t < 64) { as2[n0 + t] = asr[t]; ad2[n0 + t] = adr[t]; }
}

// ======================= K5: GAT2 edge MFMA + partial pool =======
__global__ __launch_bounds__(512) void gat2_edge_mfma(
    const unsigned short* __restrict__ ht2, const float* __restrict__ as2,
    const float* __restrict__ ad2, const unsigned int* __restrict__ cntm,
    float* __restrict__ pl8)
{
    int g = blockIdx.x, by = blockIdx.y;
    __shared__ unsigned short ht[64 * 256];
    __shared__ unsigned short Mb[32 * 256];
    __shared__ float asl[NNODE], adl[NNODE], u1[NNODE], u2[NNODE];
    __shared__ float v1[NNODE], v2[NNODE];
    __shared__ float wred[8];
    __shared__ float pool[64];
    int t = threadIdx.x;

    float va = -1e30f, vd = 0.f;
    if (t < NNODE) {
        va = as2[g * NNODE + t];
        vd = ad2[g * NNODE + t];
        asl[t] = va; adl[t] = vd;
    }
    if (t < 64) pool[t] = 0.f;
    {
        float mv = va;
        #pragma unroll
        for (int d = 32; d; d >>= 1) mv = fmaxf(mv, __shfl_xor(mv, d));
        if ((t & 63) == 0) wred[t >> 6] = mv;
    }
    __syncthreads();
    if (t < NNODE) {
        float M = fmaxf(fmaxf(wred[0], wred[1]), fmaxf(wred[2], wred[3]));
        float mt = lrelu02(M + vd);
        v1[t] = __expf(vd - mt);
        v2[t] = __expf(0.2f * vd - mt);
        u1[t] = __expf(va);
        u2[t] = __expf(0.2f * va);
    }
    for (int i = t; i < 2048; i += 512) {
        int c = i >> 5, sg = i & 31;
        bf16x8 v = *(const bf16x8*)&ht2[(size_t)(g * 64 + c) * 256 + sg * 8];
        *(bf16x8*)&ht[c * 256 + ((sg ^ (c & 31)) << 3)] = v;
    }
    __syncthreads();

    int w = t >> 6, l = t & 63;
    int lrow = l & 15, lk = l >> 4;
    int r0 = by * 32;

    // dense fill (unconditional) covers all 32 rows of Mb
    for (int ri = w; ri < 32; ri += 8) {
        int d = r0 + ri;
        unsigned cwv = cntm[(((size_t)g * NNODE + d) << 6) + l];
        float adv = adl[d], vd1 = v1[d], vd2 = v2[d];
        float4 as4 = ((const float4*)asl)[l];
        float4 u14 = ((const float4*)u1)[l];
        float4 u24 = ((const float4*)u2)[l];
        float p0 = (float)(cwv & 0xFFu) *
                   ((as4.x + adv > 0.f) ? u14.x * vd1 : u24.x * vd2);
        float p1 = (float)((cwv >> 8) & 0xFFu) *
                   ((as4.y + adv > 0.f) ? u14.y * vd1 : u24.y * vd2);
        float p2 = (float)((cwv >> 16) & 0xFFu) *
                   ((as4.z + adv > 0.f) ? u14.z * vd1 : u24.z * vd2);
        float p3 = (float)(cwv >> 24) *
                   ((as4.w + adv > 0.f) ? u14.w * vd1 : u24.w * vd2);
        *(unsigned long long*)&Mb[ri * 256 + (((l >> 1) ^ (ri & 7)) << 3)
                                  + ((l & 1) << 2)] = pk4(p0, p1, p2, p3);
    }
    __syncthreads();

    const bf16x8 onev = {(short)0x3F80, (short)0x3F80, (short)0x3F80, (short)0x3F80,
                         (short)0x3F80, (short)0x3F80, (short)0x3F80, (short)0x3F80};
    int mt = w & 1, nt = w >> 1;
    f32x4 acc = {0.f, 0.f, 0.f, 0.f};
    f32x4 accd = {0.f, 0.f, 0.f, 0.f};
    int ar = mt * 16 + lrow;
    int c = nt * 16 + lrow;
    #pragma unroll
    for (int kb = 0; kb < 8; ++kb) {
        int oct = kb * 4 + lk;
        bf16x8 a = *(const bf16x8*)&Mb[ar * 256 + ((oct ^ (ar & 7)) << 3)];
        bf16x8 b = *(const bf16x8*)&ht[c * 256 + ((oct ^ (c & 31)) << 3)];
        accd = __builtin_amdgcn_mfma_f32_16x16x32_bf16(a, onev, accd, 0, 0, 0);
        acc = __builtin_amdgcn_mfma_f32_16x16x32_bf16(a, b, acc, 0, 0, 0);
    }
    float ps = 0.f;
    #pragma unroll
    for (int r = 0; r < 4; ++r)
        ps = fmaf(acc[r], 1.f / (accd[r] + 1e-16f), ps);
    ps += __shfl_xor(ps, 16);
    ps += __shfl_xor(ps, 32);
    if (l < 16) atomicAdd(&pool[nt * 16 + lrow], ps);
    __syncthreads();
    if (t < 64) pl8[(size_t)(g * 8 + by) * 64 + t] = pool[t];
}

// ======================= K6: pool-combine + classifier ===========
__global__ __launch_bounds__(64) void cls_kernel(
    const float* __restrict__ pl8, const float* __restrict__ bias2,
    const float* __restrict__ w1, const float* __restrict__ b1,
    const float* __restrict__ w2, const float* __restrict__ b2,
    float* __restrict__ outv, float* __restrict__ pooled)
{
    int g = blockIdx.x, c = threadIdx.x;
    float po = 0.f;
    #pragma unroll
    for (int q = 0; q < 8; ++q) po += pl8[(size_t)(g * 8 + q) * 64 + c];
    po = po * (1.f / 256.f) + bias2[c];
    pooled[g * 64 + c] = po;
    __shared__ float poL[64];
    poL[c] = po;
    __syncthreads();
    float acc = b1[c];
    for (int k = 0; k < 64; ++k) acc = fmaf(poL[k], w1[k * 64 + c], acc);
    acc = fmaxf(acc, 0.f);
    float contrib = acc * w2[c];
    #pragma unroll
    for (int d = 32; d; d >>= 1) contrib += __shfl_xor(contrib, d);
    if (c == 0) outv[g] = 1.f / (1.f + __expf(-contrib));
}

extern "C" void kernel_launch(void* const* d_in, const int* in_sizes, int n_in,
                              void* d_out, int out_size, void* d_ws, size_t ws_size,
                              hipStream_t stream) {
    const float* omics   = (const float*)d_in[0];
    const float* w_omics = (const float*)d_in[1];
    const float* b_omics = (const float*)d_in[2];
    const float* rot     = (const float*)d_in[3];
    const float* bn_g    = (const float*)d_in[4];
    const float* bn_b    = (const float*)d_in[5];
    const float* bn_m    = (const float*)d_in[6];
    const float* bn_v    = (const float*)d_in[7];
    const float* gat1_w  = (const float*)d_in[8];
    const float* att_s1  = (const float*)d_in[9];
    const float* att_d1  = (const float*)d_in[10];
    const float* bias1   = (const float*)d_in[11];
    const float* gat2_w  = (const float*)d_in[12];
    const float* att_s2  = (const float*)d_in[13];
    const float* att_d2  = (const float*)d_in[14];
    const float* bias2   = (const float*)d_in[15];
    const float* cls_w1  = (const float*)d_in[16];
    const float* cls_b1  = (const float*)d_in[17];
    const float* cls_w2  = (const float*)d_in[18];
    const float* cls_b2  = (const float*)d_in[19];
    const int*   eidx    = (const int*)d_in[20];

    float* ws = (float*)d_ws;
    size_t o_xb   = 0;
    size_t o_ht1  = o_xb  + (size_t)NUM_NODES * 64 / 2;
    size_t o_as1  = o_ht1 + (size_t)G * HEADS * 64 * 256 / 2;
    size_t o_ad1  = o_as1 + (size_t)NUM_NODES * HEADS;
    size_t o_x2b  = o_ad1 + (size_t)NUM_NODES * HEADS;
    size_t o_ht2  = o_x2b + (size_t)NUM_NODES * 256 / 2;
    size_t o_as2  = o_ht2 + (size_t)G * 64 * 256 / 2;
    size_t o_ad2  = o_as2 + (size_t)NUM_NODES;
    size_t o_pl8  = o_ad2 + (size_t)NUM_NODES;
    size_t o_cnt  = o_pl8 + (size_t)G * 8 * 64;     // u32 G*16384 (4 MB)
    size_t o_wt1  = o_cnt + (size_t)G * 16384;
    size_t o_wt2  = o_wt1 + 8192;

    unsigned short* xb  = (unsigned short*)(ws + o_xb);
    unsigned short* ht1 = (unsigned short*)(ws + o_ht1);
    float* as1 = ws + o_as1;
    float* ad1 = ws + o_ad1;
    unsigned short* x2b = (unsigned short*)(ws + o_x2b);
    unsigned short* ht2 = (unsigned short*)(ws + o_ht2);
    float* as2 = ws + o_as2;
    float* ad2 = ws + o_ad2;
    float* pl8 = ws + o_pl8;
    unsigned int* cntm = (unsigned int*)(ws + o_cnt);
    unsigned short* wt1 = (unsigned short*)(ws + o_wt1);
    unsigned short* wt2 = (unsigned short*)(ws + o_wt2);

    float* outv   = (float*)d_out;        // [64]
    float* pooled = (float*)d_out + G;    // [64*64]

    setup_kernel<<<G + 256 + 8, 512, 0, stream>>>(
        eidx, cntm,
        omics, w_omics, b_omics, rot, bn_g, bn_b, bn_m, bn_v, xb,
        gat1_w, gat2_w, wt1, wt2);
    gat1_lin_mfma<<<256, 512, 0, stream>>>(xb, wt1, att_s1, att_d1, ht1, as1, ad1);
    gat1_edge_mfma<<<dim3(G, HEADS, 4), 512, 0, stream>>>(
        ht1, as1, ad1, cntm, bias1, x2b);
    gat2_lin_mfma<<<256, 512, 0, stream>>>(x2b, wt2, att_s2, att_d2, ht2, as2, ad2);
    gat2_edge_mfma<<<dim3(G, 8), 512, 0, stream>>>(
        ht2, as2, ad2, cntm, pl8);
    cls_kernel<<<G, 64, 0, stream>>>(pl8, bias2, cls_w1, cls_b1, cls_w2, cls_b2,
                                     outv, pooled);
}